// Round 1
// baseline (19.958 us; speedup 1.0000x reference)
//
#include <hip/hip_runtime.h>
#include <math.h>

// GNN_59219009077824
// B=1024, N=256, F=6, H=128, O=64
//
// Structure exploit: edge(i,j) = cond_i | cond_j among valid nodes.
// C = valid & cond, NC = valid & !cond.
//   deg_i = nv        for i in C   -> dinv = a = nv^-0.5
//   deg_i = nc+1      for i in NC  -> dinv = c = (nc+1)^-0.5
// (An Y)_i = a*S_all            for i in C   (S_all = sum_{j in V} dinv_j Y_j)
//          = c*S_c + c^2 * Y_i  for i in NC  (S_c   = sum_{j in C} dinv_j Y_j)
// Layer1 input sums via linearity: S_* from (sum_i x_i) @ W1.
// Pooled output needs only hC (one vector, shared by all C nodes) and
// hNC_sum = sum_{i in NC} relu(c*S_c + c^2 * Z_i + b1), then two H->O matvecs.

#define NB 1024
#define NN 256
#define NF 6
#define NH 128
#define NO 64

__global__ __launch_bounds__(256) void gnn_kernel(
    const float* __restrict__ x,    // [B,N,F]
    const float* __restrict__ W1,   // [F,H]
    const float* __restrict__ b1,   // [H]
    const float* __restrict__ W2,   // [H,O]
    const float* __restrict__ b2,   // [O]
    float* __restrict__ out)        // [B,O]
{
    const int b = blockIdx.x;
    const int t = threadIdx.x;

    __shared__ float xl[NN][NF];      // node features (for NC loop)
    __shared__ float xCs[NF];         // sum of x over C nodes
    __shared__ float xNCs[NF];        // sum of x over NC nodes
    __shared__ int   s_nv, s_nc, s_nnc;
    __shared__ int   nc_list[NN];     // indices of NC nodes
    __shared__ float hC[NH];          // layer-1 output shared by all C nodes
    __shared__ float hNCs[NH];        // sum of layer-1 outputs over NC nodes
    __shared__ float y2C[NO];         // hC @ W2
    __shared__ float y2NCs[NO];       // hNCs @ W2

    if (t == 0) { s_nv = 0; s_nc = 0; s_nnc = 0; }
    if (t < NF) { xCs[t] = 0.f; xNCs[t] = 0.f; }
    __syncthreads();

    // ---- Phase 1: per-node classification + masked feature sums ----
    const float* xp = x + ((size_t)b * NN + t) * NF;
    float xf[NF];
    float absum = 0.f;
    #pragma unroll
    for (int f = 0; f < NF; ++f) { xf[f] = xp[f]; absum += fabsf(xf[f]); }
    const bool valid = (absum != 0.f);
    const bool condv = valid && ((xf[3] != 0.f) || (xf[4] != 0.f));
    const bool isNC  = valid && !condv;

    #pragma unroll
    for (int f = 0; f < NF; ++f) xl[t][f] = xf[f];

    if (valid) atomicAdd(&s_nv, 1);
    if (condv) {
        atomicAdd(&s_nc, 1);
        #pragma unroll
        for (int f = 0; f < NF; ++f) atomicAdd(&xCs[f], xf[f]);
    } else if (isNC) {
        int idx = atomicAdd(&s_nnc, 1);
        nc_list[idx] = t;
        #pragma unroll
        for (int f = 0; f < NF; ++f) atomicAdd(&xNCs[f], xf[f]);
    }
    __syncthreads();

    const int nv  = s_nv;
    const int nc  = s_nc;
    const int nnc = s_nnc;

    if (nv == 0) {               // no valid nodes: output zeros
        if (t < NO) out[(size_t)b * NO + t] = 0.f;
        return;
    }

    const float a  = 1.f / sqrtf((float)nv);
    const float c  = 1.f / sqrtf((float)(nc + 1));
    const float c2 = c * c;

    // ---- Phase 2+3: layer 1 (per output channel h = t < 128) ----
    if (t < NH) {
        float w[NF];
        float zc = 0.f, znc = 0.f;
        #pragma unroll
        for (int f = 0; f < NF; ++f) {
            w[f] = W1[f * NH + t];
            zc  = fmaf(xCs[f],  w[f], zc);
            znc = fmaf(xNCs[f], w[f], znc);
        }
        const float Sc   = a * zc;             // sum_{j in C} dinv_j Z_j [h]
        const float Sall = Sc + c * znc;       // sum_{j in V} dinv_j Z_j [h]
        const float b1t  = b1[t];

        hC[t] = fmaxf(fmaf(a, Sall, b1t), 0.f);

        // NC nodes: h1_i = relu(c*Sc + c^2*Z_i + b1); accumulate their sum
        const float vloc = fmaf(c, Sc, b1t);
        float acc = 0.f;
        for (int k = 0; k < nnc; ++k) {
            const int i = nc_list[k];
            float z = 0.f;
            #pragma unroll
            for (int f = 0; f < NF; ++f) z = fmaf(xl[i][f], w[f], z);
            acc += fmaxf(fmaf(c2, z, vloc), 0.f);
        }
        hNCs[t] = acc;
    }
    __syncthreads();

    // ---- Phase 4: layer 2 matvecs (H -> O), two of them ----
    if (t < 2 * NO) {
        const int  o      = t & (NO - 1);
        const bool second = (t >= NO);
        const float* src  = second ? hNCs : hC;
        float acc = 0.f;
        #pragma unroll 8
        for (int h = 0; h < NH; ++h) acc = fmaf(src[h], W2[h * NO + o], acc);
        if (second) y2NCs[o] = acc; else y2C[o] = acc;
    }
    __syncthreads();

    // ---- Phase 5: second aggregation + valid-mean pool, closed form ----
    if (t < NO) {
        const float S2c   = a * (float)nc * y2C[t];
        const float S2all = S2c + c * y2NCs[t];
        // pooled = sum over C of (a*S2all) + sum over NC of (c*S2c + c2*Y2_i)
        //          + nv*b2
        const float pooled = (float)nc * (a * S2all)
                           + (float)(nv - nc) * (c * S2c)
                           + c2 * y2NCs[t]
                           + (float)nv * b2[t];
        out[(size_t)b * NO + t] = pooled / (float)nv;
    }
}

extern "C" void kernel_launch(void* const* d_in, const int* in_sizes, int n_in,
                              void* d_out, int out_size, void* d_ws, size_t ws_size,
                              hipStream_t stream) {
    const float* x  = (const float*)d_in[0];
    const float* W1 = (const float*)d_in[1];
    const float* b1 = (const float*)d_in[2];
    const float* W2 = (const float*)d_in[3];
    const float* b2 = (const float*)d_in[4];
    float* out = (float*)d_out;

    gnn_kernel<<<NB, NN, 0, stream>>>(x, W1, b1, W2, b2, out);
}

// Round 2
// 13.642 us; speedup vs baseline: 1.4630x; 1.4630x over previous
//
#include <hip/hip_runtime.h>
#include <math.h>

// GNN_59219009077824  — B=1024, N=256, F=6, H=128, O=64
//
// Low-rank structure: edge(i,j) = cond_i | cond_j among valid nodes.
// C = valid & cond, NC = valid & !cond.
//   dinv = a = nv^-0.5 for C;  dinv = c = (nc+1)^-0.5 for NC.
// (An Y)_i = a*S_all          for i in C
//          = c*S_c + c^2*Y_i  for i in NC
// Only block-level sums + per-NC-node ReLU are needed; pooled output is
// closed-form. Round 1: atomics -> ballot/shuffle reductions (atomics were
// the 20us bottleneck; nnc ~ 0 with random data so the NC loop is cheap).

#define NB 1024
#define NN 256
#define NF 6
#define NH 128
#define NO 64

__global__ __launch_bounds__(256) void gnn_kernel(
    const float* __restrict__ x,    // [B,N,F]
    const float* __restrict__ W1,   // [F,H]
    const float* __restrict__ b1,   // [H]
    const float* __restrict__ W2,   // [H,O]
    const float* __restrict__ b2,   // [O]
    float* __restrict__ out)        // [B,O]
{
    const int b    = blockIdx.x;
    const int t    = threadIdx.x;
    const int wid  = t >> 6;
    const int lane = t & 63;

    __shared__ float4 xc4[NN][2];    // compacted NC features (padded to 8 floats)
    __shared__ float  psum[4][12];   // per-wave partials: [w][0..5]=C, [6..11]=NC
    __shared__ int    wcnt[4][3];    // per-wave: {nv, nc, nnc}
    __shared__ float  fs[12];        // final sums: xCs[0..5], xNCs[0..5]
    __shared__ float  hC[NH];
    __shared__ float  hNCs2[2][NH];  // two partial NC-sums (split over halves)
    __shared__ float  y2C[NO];
    __shared__ float  y2NCs[NO];

    // ---- Phase 1: load + classify + wave-level reductions ----
    const float2* xp2 = (const float2*)(x + ((size_t)b * NN + t) * NF);
    float2 v0 = xp2[0], v1 = xp2[1], v2 = xp2[2];
    float xf[NF] = { v0.x, v0.y, v1.x, v1.y, v2.x, v2.y };

    float absum = fabsf(xf[0]) + fabsf(xf[1]) + fabsf(xf[2])
                + fabsf(xf[3]) + fabsf(xf[4]) + fabsf(xf[5]);
    const bool valid = (absum != 0.f);
    const bool condv = valid && ((xf[3] != 0.f) || (xf[4] != 0.f));
    const bool isNC  = valid && !condv;

    const unsigned long long mV = __ballot(valid);
    const unsigned long long mC = __ballot(condv);
    const unsigned long long mN = __ballot(isNC);

    float r[12];
    #pragma unroll
    for (int f = 0; f < NF; ++f) {
        r[f]     = condv ? xf[f] : 0.f;
        r[f + 6] = isNC  ? xf[f] : 0.f;
    }
    #pragma unroll
    for (int j = 0; j < 12; ++j) {
        #pragma unroll
        for (int off = 32; off >= 1; off >>= 1)
            r[j] += __shfl_xor(r[j], off);
    }
    if (lane == 0) {
        #pragma unroll
        for (int j = 0; j < 12; ++j) psum[wid][j] = r[j];
        wcnt[wid][0] = (int)__popcll(mV);
        wcnt[wid][1] = (int)__popcll(mC);
        wcnt[wid][2] = (int)__popcll(mN);
    }
    __syncthreads();

    // ---- Phase 1b: counts, NC compaction, final feature sums ----
    const int nv  = wcnt[0][0] + wcnt[1][0] + wcnt[2][0] + wcnt[3][0];
    const int nc  = wcnt[0][1] + wcnt[1][1] + wcnt[2][1] + wcnt[3][1];
    const int nnc = wcnt[0][2] + wcnt[1][2] + wcnt[2][2] + wcnt[3][2];

    if (isNC) {
        int off = 0;
        #pragma unroll
        for (int w = 0; w < 4; ++w) if (w < wid) off += wcnt[w][2];
        const int rank = (int)__popcll(mN & ((1ull << lane) - 1ull));
        xc4[off + rank][0] = make_float4(xf[0], xf[1], xf[2], xf[3]);
        xc4[off + rank][1] = make_float4(xf[4], xf[5], 0.f, 0.f);
    }
    if (t < 12) fs[t] = psum[0][t] + psum[1][t] + psum[2][t] + psum[3][t];
    __syncthreads();

    if (nv == 0) {                  // no valid nodes: zeros
        if (t < NO) out[(size_t)b * NO + t] = 0.f;
        return;
    }

    const float a  = 1.f / sqrtf((float)nv);
    const float c  = 1.f / sqrtf((float)(nc + 1));
    const float c2 = c * c;

    // ---- Phase 2: layer 1 (g = which half of NC nodes, h = channel) ----
    {
        const int g = t >> 7;       // 0 or 1
        const int h = t & (NH - 1);
        float w8[8];
        #pragma unroll
        for (int f = 0; f < NF; ++f) w8[f] = W1[f * NH + h];
        w8[6] = 0.f; w8[7] = 0.f;

        float zc = 0.f, znc = 0.f;
        #pragma unroll
        for (int f = 0; f < NF; ++f) {
            zc  = fmaf(fs[f],     w8[f], zc);
            znc = fmaf(fs[f + 6], w8[f], znc);
        }
        const float Sc   = a * zc;
        const float Sall = Sc + c * znc;
        const float b1t  = b1[h];

        if (g == 0) hC[h] = fmaxf(fmaf(a, Sall, b1t), 0.f);

        const float vloc = fmaf(c, Sc, b1t);
        float acc = 0.f;
        for (int k = g; k < nnc; k += 2) {
            const float4 u0 = xc4[k][0];
            const float4 u1 = xc4[k][1];
            float z = u0.x * w8[0];
            z = fmaf(u0.y, w8[1], z);
            z = fmaf(u0.z, w8[2], z);
            z = fmaf(u0.w, w8[3], z);
            z = fmaf(u1.x, w8[4], z);
            z = fmaf(u1.y, w8[5], z);
            acc += fmaxf(fmaf(c2, z, vloc), 0.f);
        }
        hNCs2[g][h] = acc;
    }
    __syncthreads();

    // ---- Phase 3: layer 2 matvecs (H -> O), two of them ----
    if (t < 2 * NO) {
        const int  o      = t & (NO - 1);
        const bool second = (t >= NO);     // wave-uniform
        const float4* hv0 = (const float4*)(second ? hNCs2[0] : hC);
        const float4* hv1 = (const float4*)hNCs2[1];
        float acc = 0.f;
        #pragma unroll
        for (int h4 = 0; h4 < NH / 4; ++h4) {
            float4 s = hv0[h4];
            if (second) {
                const float4 s1 = hv1[h4];
                s.x += s1.x; s.y += s1.y; s.z += s1.z; s.w += s1.w;
            }
            const int h = h4 * 4;
            acc = fmaf(s.x, W2[(h + 0) * NO + o], acc);
            acc = fmaf(s.y, W2[(h + 1) * NO + o], acc);
            acc = fmaf(s.z, W2[(h + 2) * NO + o], acc);
            acc = fmaf(s.w, W2[(h + 3) * NO + o], acc);
        }
        if (second) y2NCs[o] = acc; else y2C[o] = acc;
    }
    __syncthreads();

    // ---- Phase 4: second aggregation + valid-mean pool, closed form ----
    if (t < NO) {
        const float S2c   = a * (float)nc * y2C[t];
        const float S2all = S2c + c * y2NCs[t];
        const float pooled = (float)nc * (a * S2all)
                           + (float)(nv - nc) * (c * S2c)
                           + c2 * y2NCs[t]
                           + (float)nv * b2[t];
        out[(size_t)b * NO + t] = pooled / (float)nv;
    }
}

extern "C" void kernel_launch(void* const* d_in, const int* in_sizes, int n_in,
                              void* d_out, int out_size, void* d_ws, size_t ws_size,
                              hipStream_t stream) {
    const float* x  = (const float*)d_in[0];
    const float* W1 = (const float*)d_in[1];
    const float* b1 = (const float*)d_in[2];
    const float* W2 = (const float*)d_in[3];
    const float* b2 = (const float*)d_in[4];
    float* out = (float*)d_out;

    gnn_kernel<<<NB, NN, 0, stream>>>(x, W1, b1, W2, b2, out);
}

// Round 4
// 11.824 us; speedup vs baseline: 1.6878x; 1.1537x over previous
//
#include <hip/hip_runtime.h>
#include <math.h>

// GNN_59219009077824  — B=1024, N=256, F=6, H=128, O=64
//
// Low-rank structure: edge(i,j) = cond_i | cond_j among valid nodes.
// C = valid & cond, NC = valid & !cond.
//   dinv = a = nv^-0.5 for C;  dinv = c = (nc+1)^-0.5 for NC.
// (An Y)_i = a*S_all          for i in C
//          = c*S_c + c^2*Y_i  for i in NC
// Pooled output is closed-form from two masked feature sums + per-NC ReLUs.
// R1: LDS atomics -> ballot/shuffle (20.0 -> 13.6 us).
// R2/R3: shuffle butterfly (72 DS ops) -> DPP VALU reduction (template args:
// update_dpp requires literal constants); prefetch W1/b1/b2 at kernel entry.

#define NB 1024
#define NN 256
#define NF 6
#define NH 128
#define NO 64

// v_add_f32 with DPP-moved operand; old=0 so masked-off lanes add 0.
template <int CTRL, int ROW_MASK, int BANK_MASK>
__device__ __forceinline__ float dpp_add(float v) {
    int moved = __builtin_amdgcn_update_dpp(0, __float_as_int(v),
                                            CTRL, ROW_MASK, BANK_MASK, true);
    return v + __int_as_float(moved);
}

// Full 64-lane sum; result valid in lane 63. Canonical gfx9 DPP sequence.
__device__ __forceinline__ float wave_sum64(float v) {
    v = dpp_add<0x111, 0xf, 0xf>(v); // row_shr:1
    v = dpp_add<0x112, 0xf, 0xf>(v); // row_shr:2
    v = dpp_add<0x114, 0xf, 0xe>(v); // row_shr:4
    v = dpp_add<0x118, 0xf, 0xc>(v); // row_shr:8
    v = dpp_add<0x142, 0xa, 0xf>(v); // row_bcast:15
    v = dpp_add<0x143, 0xc, 0xf>(v); // row_bcast:31
    return v;
}

__global__ __launch_bounds__(256) void gnn_kernel(
    const float* __restrict__ x,    // [B,N,F]
    const float* __restrict__ W1,   // [F,H]
    const float* __restrict__ b1,   // [H]
    const float* __restrict__ W2,   // [H,O]
    const float* __restrict__ b2,   // [O]
    float* __restrict__ out)        // [B,O]
{
    const int b    = blockIdx.x;
    const int t    = threadIdx.x;
    const int wid  = t >> 6;
    const int lane = t & 63;
    const int h    = t & (NH - 1);

    __shared__ float4 xc4[NN][2];    // compacted NC features (8 floats/node)
    __shared__ float  psum[4][12];   // per-wave partials: [w][0..5]=C, [6..11]=NC
    __shared__ int    wcnt[4][3];    // per-wave: {nv, nc, nnc}
    __shared__ float  fs[12];        // final sums: xCs[0..5], xNCs[0..5]
    __shared__ float  hC[NH];
    __shared__ float  hNCs2[2][NH];  // partial NC sums (split over halves)
    __shared__ float  y2C[NO];
    __shared__ float  y2NCs[NO];

    // ---- Prefetch weights: issue at entry, latency hides under phase 1 ----
    float w1r[NF];
    #pragma unroll
    for (int f = 0; f < NF; ++f) w1r[f] = W1[f * NH + h];
    const float b1r = b1[h];
    const float b2r = b2[t & (NO - 1)];

    // ---- Phase 1: load + classify + DPP wave reductions ----
    const float2* xp2 = (const float2*)(x + ((size_t)b * NN + t) * NF);
    float2 v0 = xp2[0], v1 = xp2[1], v2 = xp2[2];
    float xf[NF] = { v0.x, v0.y, v1.x, v1.y, v2.x, v2.y };

    float absum = fabsf(xf[0]) + fabsf(xf[1]) + fabsf(xf[2])
                + fabsf(xf[3]) + fabsf(xf[4]) + fabsf(xf[5]);
    const bool valid = (absum != 0.f);
    const bool condv = valid && ((xf[3] != 0.f) || (xf[4] != 0.f));
    const bool isNC  = valid && !condv;

    const unsigned long long mV = __ballot(valid);
    const unsigned long long mC = __ballot(condv);
    const unsigned long long mN = __ballot(isNC);

    float r[12];
    #pragma unroll
    for (int f = 0; f < NF; ++f) {
        r[f]     = condv ? xf[f] : 0.f;
        r[f + 6] = isNC  ? xf[f] : 0.f;
    }
    #pragma unroll
    for (int j = 0; j < 12; ++j) r[j] = wave_sum64(r[j]);

    if (lane == 63) {
        #pragma unroll
        for (int j = 0; j < 12; ++j) psum[wid][j] = r[j];
        wcnt[wid][0] = (int)__popcll(mV);
        wcnt[wid][1] = (int)__popcll(mC);
        wcnt[wid][2] = (int)__popcll(mN);
    }
    __syncthreads();

    // ---- Phase 1b: counts, NC compaction, final feature sums ----
    const int nv  = wcnt[0][0] + wcnt[1][0] + wcnt[2][0] + wcnt[3][0];
    const int nc  = wcnt[0][1] + wcnt[1][1] + wcnt[2][1] + wcnt[3][1];
    const int nnc = wcnt[0][2] + wcnt[1][2] + wcnt[2][2] + wcnt[3][2];

    if (isNC) {
        int off = 0;
        #pragma unroll
        for (int w = 0; w < 4; ++w) if (w < wid) off += wcnt[w][2];
        const int rank = (int)__popcll(mN & ((1ull << lane) - 1ull));
        xc4[off + rank][0] = make_float4(xf[0], xf[1], xf[2], xf[3]);
        xc4[off + rank][1] = make_float4(xf[4], xf[5], 0.f, 0.f);
    }
    if (t < 12) fs[t] = psum[0][t] + psum[1][t] + psum[2][t] + psum[3][t];
    __syncthreads();

    if (nv == 0) {                  // no valid nodes: zeros
        if (t < NO) out[(size_t)b * NO + t] = 0.f;
        return;
    }

    const float a  = 1.f / sqrtf((float)nv);
    const float c  = 1.f / sqrtf((float)(nc + 1));
    const float c2 = c * c;

    // ---- Phase 2: layer 1 (g = NC-half, h = channel) ----
    {
        const int g = t >> 7;       // 0 or 1
        float zc = 0.f, znc = 0.f;
        #pragma unroll
        for (int f = 0; f < NF; ++f) {
            zc  = fmaf(fs[f],     w1r[f], zc);
            znc = fmaf(fs[f + 6], w1r[f], znc);
        }
        const float Sc   = a * zc;
        const float Sall = Sc + c * znc;

        if (g == 0) hC[h] = fmaxf(fmaf(a, Sall, b1r), 0.f);

        const float vloc = fmaf(c, Sc, b1r);
        float acc = 0.f;
        for (int k = g; k < nnc; k += 2) {
            const float4 u0 = xc4[k][0];
            const float4 u1 = xc4[k][1];
            float z = u0.x * w1r[0];
            z = fmaf(u0.y, w1r[1], z);
            z = fmaf(u0.z, w1r[2], z);
            z = fmaf(u0.w, w1r[3], z);
            z = fmaf(u1.x, w1r[4], z);
            z = fmaf(u1.y, w1r[5], z);
            acc += fmaxf(fmaf(c2, z, vloc), 0.f);
        }
        hNCs2[g][h] = acc;
    }
    __syncthreads();

    // ---- Phase 3: layer 2 matvecs (H -> O), two of them ----
    if (t < 2 * NO) {
        const int  o      = t & (NO - 1);
        const bool second = (t >= NO);     // wave-uniform
        const float4* hv0 = (const float4*)(second ? hNCs2[0] : hC);
        const float4* hv1 = (const float4*)hNCs2[1];
        float acc = 0.f;
        #pragma unroll
        for (int h4 = 0; h4 < NH / 4; ++h4) {
            float4 s = hv0[h4];
            if (second) {
                const float4 s1 = hv1[h4];
                s.x += s1.x; s.y += s1.y; s.z += s1.z; s.w += s1.w;
            }
            const int hh = h4 * 4;
            acc = fmaf(s.x, W2[(hh + 0) * NO + o], acc);
            acc = fmaf(s.y, W2[(hh + 1) * NO + o], acc);
            acc = fmaf(s.z, W2[(hh + 2) * NO + o], acc);
            acc = fmaf(s.w, W2[(hh + 3) * NO + o], acc);
        }
        if (second) y2NCs[o] = acc; else y2C[o] = acc;
    }
    __syncthreads();

    // ---- Phase 4: second aggregation + valid-mean pool, closed form ----
    if (t < NO) {
        const float S2c   = a * (float)nc * y2C[t];
        const float S2all = S2c + c * y2NCs[t];
        const float pooled = (float)nc * (a * S2all)
                           + (float)(nv - nc) * (c * S2c)
                           + c2 * y2NCs[t]
                           + (float)nv * b2r;
        out[(size_t)b * NO + t] = pooled / (float)nv;
    }
}

extern "C" void kernel_launch(void* const* d_in, const int* in_sizes, int n_in,
                              void* d_out, int out_size, void* d_ws, size_t ws_size,
                              hipStream_t stream) {
    const float* x  = (const float*)d_in[0];
    const float* W1 = (const float*)d_in[1];
    const float* b1 = (const float*)d_in[2];
    const float* W2 = (const float*)d_in[3];
    const float* b2 = (const float*)d_in[4];
    float* out = (float*)d_out;

    gnn_kernel<<<NB, NN, 0, stream>>>(x, W1, b1, W2, b2, out);
}

// Round 5
// 9.938 us; speedup vs baseline: 2.0081x; 1.1898x over previous
//
#include <hip/hip_runtime.h>
#include <math.h>

// GNN_59219009077824  — B=1024, N=256, F=6, H=128, O=64
//
// Low-rank structure: edge(i,j) = cond_i | cond_j among valid nodes.
// C = valid & cond, NC = valid & !cond.
//   dinv = a = nv^-0.5 for C;  dinv = c = (nc+1)^-0.5 for NC.
// (An Y)_i = a*S_all for i in C;  c*S_c + c^2*Y_i for i in NC.
// Pooled output is closed-form from two masked feature sums + per-NC ReLUs.
// R1: LDS atomics -> ballot/shuffle (20.0 -> 13.6 us).
// R2-4: DPP wave reduction + weight prefetch (13.6 -> 11.8 us).
// R5: ONE WAVE PER BATCH — zero cross-wave barriers, 4 nodes/lane in regs,
//     readlane broadcast of reduced sums, lane==h-pair for L1, lane==o for L2.
//     Only LDS use: 256-float h-transpose inside a single wave.

#define NB 1024
#define NN 256
#define NF 6
#define NH 128
#define NO 64

// v_add_f32 with DPP-moved operand; old=0 so masked-off lanes add 0.
template <int CTRL, int ROW_MASK, int BANK_MASK>
__device__ __forceinline__ float dpp_add(float v) {
    int moved = __builtin_amdgcn_update_dpp(0, __float_as_int(v),
                                            CTRL, ROW_MASK, BANK_MASK, true);
    return v + __int_as_float(moved);
}

// Full 64-lane sum; result valid in lane 63. Canonical gfx9 DPP sequence.
__device__ __forceinline__ float wave_sum64(float v) {
    v = dpp_add<0x111, 0xf, 0xf>(v); // row_shr:1
    v = dpp_add<0x112, 0xf, 0xf>(v); // row_shr:2
    v = dpp_add<0x114, 0xf, 0xe>(v); // row_shr:4
    v = dpp_add<0x118, 0xf, 0xc>(v); // row_shr:8
    v = dpp_add<0x142, 0xa, 0xf>(v); // row_bcast:15
    v = dpp_add<0x143, 0xc, 0xf>(v); // row_bcast:31
    return v;
}

__device__ __forceinline__ float bcast63(float v) {
    return __int_as_float(__builtin_amdgcn_readlane(__float_as_int(v), 63));
}

__global__ __launch_bounds__(64) void gnn_kernel(
    const float* __restrict__ x,    // [B,N,F]
    const float* __restrict__ W1,   // [F,H]
    const float* __restrict__ b1,   // [H]
    const float* __restrict__ W2,   // [H,O]
    const float* __restrict__ b2,   // [O]
    float* __restrict__ out)        // [B,O]
{
    const int b    = blockIdx.x;
    const int lane = threadIdx.x;   // 0..63, one wave per batch

    __shared__ float hC_s[NH];      // layer-1 C-node output (transpose buffer)
    __shared__ float hN_s[NH];      // layer-1 NC-sum (transpose buffer)

    // ---- Prefetch weights; latency overlaps the x loads ----
    float w1a[NF], w1b[NF];
    #pragma unroll
    for (int f = 0; f < NF; ++f) {
        w1a[f] = W1[f * NH + lane];
        w1b[f] = W1[f * NH + lane + 64];
    }
    const float b1a = b1[lane];
    const float b1b = b1[lane + 64];
    const float b2r = b2[lane];

    // ---- Load 4 nodes/lane, classify, per-lane accumulate ----
    const float* xb = x + (size_t)b * NN * NF;
    float xf[4][NF];
    bool  ncf[4];
    float r[15];                    // 0..5 C-sums, 6..11 NC-sums, 12 nv, 13 nc, 14 nnc
    #pragma unroll
    for (int j = 0; j < 15; ++j) r[j] = 0.f;

    #pragma unroll
    for (int k = 0; k < 4; ++k) {
        const float2* p = (const float2*)(xb + (size_t)(lane + 64 * k) * NF);
        float2 u0 = p[0], u1 = p[1], u2 = p[2];
        xf[k][0] = u0.x; xf[k][1] = u0.y; xf[k][2] = u1.x;
        xf[k][3] = u1.y; xf[k][4] = u2.x; xf[k][5] = u2.y;

        float absum = fabsf(xf[k][0]) + fabsf(xf[k][1]) + fabsf(xf[k][2])
                    + fabsf(xf[k][3]) + fabsf(xf[k][4]) + fabsf(xf[k][5]);
        const bool valid = (absum != 0.f);
        const bool condv = valid && ((xf[k][3] != 0.f) || (xf[k][4] != 0.f));
        const bool isNC  = valid && !condv;
        ncf[k] = isNC;

        if (valid) r[12] += 1.f;
        if (condv) {
            r[13] += 1.f;
            #pragma unroll
            for (int f = 0; f < NF; ++f) r[f] += xf[k][f];
        } else if (isNC) {
            r[14] += 1.f;
            #pragma unroll
            for (int f = 0; f < NF; ++f) r[f + 6] += xf[k][f];
        }
    }

    // ---- Wave reduction (DPP, VALU-only) + SGPR broadcast ----
    #pragma unroll
    for (int j = 0; j < 15; ++j) r[j] = wave_sum64(r[j]);

    float fs[12];
    #pragma unroll
    for (int j = 0; j < 12; ++j) fs[j] = bcast63(r[j]);
    const int nv  = (int)bcast63(r[12]);
    const int nc  = (int)bcast63(r[13]);
    const int nnc = (int)bcast63(r[14]);

    if (nv == 0) {                  // no valid nodes: zeros
        out[(size_t)b * NO + lane] = 0.f;
        return;
    }

    const float a  = 1.f / sqrtf((float)nv);
    const float c  = 1.f / sqrtf((float)(nc + 1));
    const float c2 = c * c;

    // ---- Layer 1: lane handles channels h=lane and h=lane+64 ----
    float zc0 = 0.f, zn0 = 0.f, zc1 = 0.f, zn1 = 0.f;
    #pragma unroll
    for (int f = 0; f < NF; ++f) {
        zc0 = fmaf(fs[f],     w1a[f], zc0);
        zn0 = fmaf(fs[f + 6], w1a[f], zn0);
        zc1 = fmaf(fs[f],     w1b[f], zc1);
        zn1 = fmaf(fs[f + 6], w1b[f], zn1);
    }
    const float Sc0   = a * zc0,            Sc1   = a * zc1;
    const float Sall0 = Sc0 + c * zn0,      Sall1 = Sc1 + c * zn1;

    const float hCa = fmaxf(fmaf(a, Sall0, b1a), 0.f);
    const float hCb = fmaxf(fmaf(a, Sall1, b1b), 0.f);

    // NC nodes: sum_i relu(c*Sc + c2*Z_i + b1). Empty when nnc==0 (bench case).
    float acc0 = 0.f, acc1 = 0.f;
    if (nnc > 0) {
        const float vl0 = fmaf(c, Sc0, b1a);
        const float vl1 = fmaf(c, Sc1, b1b);
        #pragma unroll
        for (int k = 0; k < 4; ++k) {
            unsigned long long m = __ballot(ncf[k]);   // wave-uniform
            while (m) {
                const int l = (int)__ffsll((long long)m) - 1;
                m &= m - 1;
                float sf[NF];
                #pragma unroll
                for (int f = 0; f < NF; ++f)
                    sf[f] = __int_as_float(
                        __builtin_amdgcn_readlane(__float_as_int(xf[k][f]), l));
                float z0 = 0.f, z1 = 0.f;
                #pragma unroll
                for (int f = 0; f < NF; ++f) {
                    z0 = fmaf(sf[f], w1a[f], z0);
                    z1 = fmaf(sf[f], w1b[f], z1);
                }
                acc0 += fmaxf(fmaf(c2, z0, vl0), 0.f);
                acc1 += fmaxf(fmaf(c2, z1, vl1), 0.f);
            }
        }
    }

    // ---- h-transpose through LDS (single wave; barrier is trivial) ----
    hC_s[lane]      = hCa;
    hC_s[lane + 64] = hCb;
    hN_s[lane]      = acc0;
    hN_s[lane + 64] = acc1;
    __syncthreads();

    // ---- Layer 2: lane == output channel o; two H->O matvecs fused ----
    const float4* hv = (const float4*)hC_s;
    const float4* nv4 = (const float4*)hN_s;
    float y2C = 0.f, y2N = 0.f;
    #pragma unroll
    for (int h4 = 0; h4 < NH / 4; ++h4) {
        const float4 sC = hv[h4];
        const float4 sN = nv4[h4];
        const int hh = h4 * 4;
        const float w0 = W2[(hh + 0) * NO + lane];
        const float w1 = W2[(hh + 1) * NO + lane];
        const float w2 = W2[(hh + 2) * NO + lane];
        const float w3 = W2[(hh + 3) * NO + lane];
        y2C = fmaf(sC.x, w0, y2C);  y2N = fmaf(sN.x, w0, y2N);
        y2C = fmaf(sC.y, w1, y2C);  y2N = fmaf(sN.y, w1, y2N);
        y2C = fmaf(sC.z, w2, y2C);  y2N = fmaf(sN.z, w2, y2N);
        y2C = fmaf(sC.w, w3, y2C);  y2N = fmaf(sN.w, w3, y2N);
    }

    // ---- Second aggregation + valid-mean pool, closed form ----
    const float S2c   = a * (float)nc * y2C;
    const float S2all = S2c + c * y2N;
    const float pooled = (float)nc * (a * S2all)
                       + (float)(nv - nc) * (c * S2c)
                       + c2 * y2N
                       + (float)nv * b2r;
    out[(size_t)b * NO + lane] = pooled / (float)nv;
}

extern "C" void kernel_launch(void* const* d_in, const int* in_sizes, int n_in,
                              void* d_out, int out_size, void* d_ws, size_t ws_size,
                              hipStream_t stream) {
    const float* x  = (const float*)d_in[0];
    const float* W1 = (const float*)d_in[1];
    const float* b1 = (const float*)d_in[2];
    const float* W2 = (const float*)d_in[3];
    const float* b2 = (const float*)d_in[4];
    float* out = (float*)d_out;

    gnn_kernel<<<NB, 64, 0, stream>>>(x, W1, b1, W2, b2, out);
}